// Round 2
// baseline (2785.889 us; speedup 1.0000x reference)
//
#include <hip/hip_runtime.h>
#include <hip/hip_fp16.h>

#define HID   1024
#define NBAT  64
#define NBLK  256
#define NTHR  256
#define AROW  2056              // 2048 + 8 pad (f16 elems)
#define AVEC  257               // AROW/8
#define PLANE 65536             // f16 elems per activation plane: [256 blk][64 n][4 j]

typedef _Float16 f16;
typedef unsigned long long u64;
typedef __attribute__((ext_vector_type(8))) _Float16 f16x8;
typedef __attribute__((ext_vector_type(4))) float f32x4;

// LDS layout (bytes)
#define A_BYTES   (2 * 16 * AROW * 2)    // 131584
#define SCR_OFF   A_BYTES                // f32 [4 kg][16 rows][64 batch] = 16384
#define C_OFF     (SCR_OFF + 16384)      // f32 [2][4][64] = 2048
#define BIAS_OFF  (C_OFF + 2048)         // f32 [2][16] = 128
#define HS_OFF    (BIAS_OFF + 128)       // f16 [64][4] = 512
#define LDS_BYTES (HS_OFF + 512)         // 150656 < 160 KiB

// barrier ints (256B-spaced): leaf i: bar[64*i] i<16 | xcd elect x: bar[64*(33+x)]
#define BAR_INTS  (64 * 41)

__device__ __forceinline__ float sigm(float x) { return 1.f / (1.f + __expf(-x)); }
__device__ __forceinline__ float tanh_f(float x) {
  float xc = fminf(fmaxf(x, -10.f), 10.f);
  float e = __expf(2.f * xc);
  return (e - 1.f) / (e + 1.f);
}

// write-through store (coherent via MALL)
__device__ __forceinline__ void st64c(void* p, u64 v) {
  __hip_atomic_store((u64*)p, v, __ATOMIC_RELAXED, __HIP_MEMORY_SCOPE_AGENT);
}

__global__ void bar_init(int* bar) {
  int i = threadIdx.x;
  #pragma unroll
  for (int k = 0; k < 3; ++k) {
    int idx = i + k * 1024;
    if (idx < BAR_INTS) bar[idx] = 0;
  }
}

// Block b owns hidden units [4b,4b+4) for both layers. Weights f16 in LDS.
// Software-pipelined slots p = 2t+L (256 total). Slot p:
//   WAIT(p-1) -> ih-GEMM(p) [K=1024, accumulates onto hh(p) partials carried
//   in VGPRs] -> elementwise -> h store -> ARRIVE(p) -> shadow: hh-GEMM(p+1)
//   -> leader buffer_inv -> WAIT.
// Barrier (R2): FLAT fire-and-forget arrival + all-blocks pipelined 16-leaf
// poll sweep. Old tree (leaf RT -> root RT -> release RT -> poll RT ~2.8us
// serialized) replaced by one one-way add (~0.35us, hidden by shadow) plus
// one poll-sweep RT (~0.7us). Monotone counters: partial-snapshot sums are
// a lower bound, so `sum >= 256*epoch` can never falsely release.
__global__ __launch_bounds__(NTHR, 1) void lstm_kernel(
    const float* __restrict__ x0, const float* __restrict__ h0,
    const float* __restrict__ c0, const float* __restrict__ Wih,
    const float* __restrict__ Whh, const float* __restrict__ bih,
    const float* __restrict__ bhh, const int* __restrict__ lenp,
    float* __restrict__ out, int* __restrict__ bar, f16* __restrict__ planes)
{
  extern __shared__ char smem[];
  f16*   Alds  = (f16*)smem;
  float* scr   = (float*)(smem + SCR_OFF);
  float* cS    = (float*)(smem + C_OFF);
  float* biasS = (float*)(smem + BIAS_OFF);
  f16*   hS    = (f16*)(smem + HS_OFF);     // [n][j] transpose buffer

  const int tid  = threadIdx.x;
  const int blk  = blockIdx.x;
  const int wave = tid >> 6;
  const int lane = tid & 63;
  const int quad = lane >> 4;
  const int l15  = lane & 15;
  const int T    = *lenp;

  f16* l0P[2] = { planes,             planes + PLANE };
  f16* l1P[2] = { planes + 2 * PLANE, planes + 3 * PLANE };
  f16* xP     =   planes + 4 * PLANE;

  int* leaf = bar + 64 * (blk & 15);

  // ---- physical XCD id + one-time leader election ----
  unsigned xcc;
  asm volatile("s_getreg_b32 %0, hwreg(HW_REG_XCC_ID)" : "=s"(xcc));
  xcc &= 7;
  int is_leader = 0;
  if (tid == 0) {
    int p = __hip_atomic_fetch_add(bar + 64 * (33 + xcc), 1, __ATOMIC_RELAXED,
                                   __HIP_MEMORY_SCOPE_AGENT);
    is_leader = (p == 0);
  }

  // ---- stage weights (f32 -> f16) into LDS ----
  {
    int r    = tid >> 2;
    int part = tid & 3;
    int l    = r >> 5;
    int m    = (r >> 1) & 15;
    int half = r & 1;
    int g    = m >> 2, j = m & 3;
    size_t grow = (size_t)g * HID + blk * 4 + j;
    const float* srcW = (half ? Whh : Wih) + ((size_t)l * 4 * HID + grow) * HID + part * 256;
    f16x8* dst = (f16x8*)(Alds + (size_t)(l * 16 + m) * AROW + half * HID + part * 256);
    const float4* s4 = (const float4*)srcW;
    #pragma unroll 4
    for (int i = 0; i < 32; ++i) {
      float4 w0 = s4[2 * i], w1 = s4[2 * i + 1];
      f16x8 o = {(f16)w0.x, (f16)w0.y, (f16)w0.z, (f16)w0.w,
                 (f16)w1.x, (f16)w1.y, (f16)w1.z, (f16)w1.w};
      dst[i] = o;
    }
  }
  // ---- biases ----
  if (tid < 32) {
    int l = tid >> 4, m = tid & 15;
    int g = m >> 2, j = m & 3;
    size_t row = (size_t)g * HID + blk * 4 + j;
    biasS[l * 16 + m] = bih[(size_t)l * 4 * HID + row] + bhh[(size_t)l * 4 * HID + row];
  }
  // ---- c state (LDS, CU-local) ----
  {
    int j = tid >> 6, n = tid & 63;
    #pragma unroll
    for (int l = 0; l < 2; ++l)
      cS[l * 256 + j * 64 + n] =
          c0[(size_t)l * NBAT * HID + (size_t)n * HID + blk * 4 + j];
  }
  // ---- h0 -> parity-1 planes (block-contiguous, 8B/lane) ----
  if (tid < 128) {
    int l = tid >> 6, n = tid & 63;
    const float* hp = h0 + (size_t)l * NBAT * HID + (size_t)n * HID + blk * 4;
    union { u64 q; f16 h[4]; } pk;
    pk.h[0] = (f16)hp[0]; pk.h[1] = (f16)hp[1]; pk.h[2] = (f16)hp[2]; pk.h[3] = (f16)hp[3];
    st64c((l == 0 ? l0P[1] : l1P[1]) + blk * 256 + n * 4, pk.q);
  }
  // ---- x0 -> xP (each block stages its own 4-unit slot) ----
  if (tid < 64) {
    int n = tid;
    const float* xp = x0 + (size_t)n * HID + blk * 4;
    union { u64 q; f16 h[4]; } pk;
    pk.h[0] = (f16)xp[0]; pk.h[1] = (f16)xp[1]; pk.h[2] = (f16)xp[2]; pk.h[3] = (f16)xp[3];
    st64c(xP + blk * 256 + n * 4, pk.q);
  }
  // one-time safety inv (poison/stale lines) before first arrival
  if (wave == 0) asm volatile("buffer_inv sc1" ::: "memory");

  // ---- flat grid barrier: fire-and-forget arrive, pipelined 16-leaf poll ----
  int epoch = 0;

  #define ARRIVE()                                                              \
    do {                                                                        \
      asm volatile("s_waitcnt vmcnt(0)" ::: "memory");                          \
      if (tid == 0)                                                             \
        (void)__hip_atomic_fetch_add(leaf, 1, __ATOMIC_RELAXED,                 \
                                     __HIP_MEMORY_SCOPE_AGENT);                 \
    } while (0)

  #define WAIT_REL()                                                            \
    do {                                                                        \
      epoch++;                                                                  \
      if (tid == 0) {                                                           \
        for (;;) {                                                              \
          int s_ = 0;                                                           \
          _Pragma("unroll")                                                     \
          for (int i_ = 0; i_ < 16; ++i_)                                       \
            s_ += __hip_atomic_fetch_add(bar + 64 * i_, 0, __ATOMIC_RELAXED,    \
                                         __HIP_MEMORY_SCOPE_AGENT);             \
          if (s_ >= 256 * epoch) break;                                         \
          __builtin_amdgcn_s_sleep(2);                                          \
        }                                                                       \
      }                                                                         \
      __syncthreads();                                                          \
    } while (0)

  // initial barrier: staging used waves 0-1, so drain+syncthreads BEFORE
  // tid0's arrival (tid0's own vmcnt only covers wave0)
  asm volatile("s_waitcnt vmcnt(0)" ::: "memory");
  __syncthreads();
  ARRIVE();
  WAIT_REL();

  const f16x8* Av = (const f16x8*)Alds;
  const f32x4 fz = {0.f, 0.f, 0.f, 0.f};
  f32x4 a0, a1, a2, a3;

  // one K=1024 GEMM over a full activation plane; wave w covers plane units
  // [w*256, w*256+256). A-frag chunk aoff walks the matching K-slice.
  auto gemmK256 = [&](const f16* psrc, int aoff) {
    const f16* p0 = psrc + (wave * 64 + quad * 2) * 256 + l15 * 4;
    #pragma unroll
    for (int kk = 0; kk < 8; ++kk) {
      f16x8 af = Av[aoff + kk * 4];
      const f16* k0 = p0 + kk * 2048;
      union { u64 q[2]; f16x8 v; } b0, b1, b2, b3;
      b0.q[0] = *(const u64*)(k0 +   0); b0.q[1] = *(const u64*)(k0 + 256);
      b1.q[0] = *(const u64*)(k0 +  64); b1.q[1] = *(const u64*)(k0 + 320);
      b2.q[0] = *(const u64*)(k0 + 128); b2.q[1] = *(const u64*)(k0 + 384);
      b3.q[0] = *(const u64*)(k0 + 192); b3.q[1] = *(const u64*)(k0 + 448);
      a0 = __builtin_amdgcn_mfma_f32_16x16x32_f16(af, b0.v, a0, 0, 0, 0);
      a1 = __builtin_amdgcn_mfma_f32_16x16x32_f16(af, b1.v, a1, 0, 0, 0);
      a2 = __builtin_amdgcn_mfma_f32_16x16x32_f16(af, b2.v, a2, 0, 0, 0);
      a3 = __builtin_amdgcn_mfma_f32_16x16x32_f16(af, b3.v, a3, 0, 0, 0);
    }
  };

  // ---- prologue: hh(t=0,l=0) from the initial h0 plane (parity 1) ----
  a0 = fz; a1 = fz; a2 = fz; a3 = fz;
  gemmK256(l0P[1], (0 * 16 + l15) * AVEC + 128 + wave * 32 + quad);

  const int NP = 2 * T;
  #pragma unroll 1
  for (int p = 0; p < NP; ++p) {
    const int L = p & 1, t = p >> 1, wp = t & 1, rp = wp ^ 1;
    if (p) WAIT_REL();

    // ---- ih-GEMM(p): operand written at slot p-1, visible per WAIT ----
    const f16* pIh = L ? l0P[wp] : (t ? l1P[rp] : xP);
    gemmK256(pIh, (L * 16 + l15) * AVEC + wave * 32 + quad);

    // ---- partials (hh(p)+ih(p)) to LDS scratch ----
    float* sc = scr + wave * 1024;
    #pragma unroll
    for (int r = 0; r < 4; ++r) {
      int base = (quad * 4 + r) * 64 + l15;
      sc[base +  0] = a0[r];
      sc[base + 16] = a1[r];
      sc[base + 32] = a2[r];
      sc[base + 48] = a3[r];
    }
    __syncthreads();

    // ---- elementwise: thread = (unit j, batch n) ----
    {
      int j = tid >> 6, n = tid & 63;
      float gate[4];
      #pragma unroll
      for (int g = 0; g < 4; ++g) {
        int b0i = (g * 4 + j) * 64 + n;
        gate[g] = scr[b0i] + scr[1024 + b0i] + scr[2048 + b0i] + scr[3072 + b0i]
                + biasS[L * 16 + g * 4 + j];
      }
      float cold = cS[L * 256 + j * 64 + n];
      float cn = sigm(gate[1]) * cold + sigm(gate[0]) * tanh_f(gate[2]);
      float hn = sigm(gate[3]) * tanh_f(cn);
      cS[L * 256 + j * 64 + n] = cn;
      hS[n * 4 + j] = (f16)hn;
    }
    __syncthreads();

    // ---- h store: ONE contiguous 512B chunk per block (+ out on L==1) ----
    if (tid < 64) {
      int n = tid;
      union { u64 q; f16 h[4]; } pk;
      pk.q = *(const u64*)(hS + n * 4);
      st64c((L == 0 ? l0P[wp] : l1P[wp]) + blk * 256 + n * 4, pk.q);
      if (L == 1) {
        union { u64 q; float f[2]; } o0, o1;
        o0.f[0] = (float)pk.h[0]; o0.f[1] = (float)pk.h[1];
        o1.f[0] = (float)pk.h[2]; o1.f[1] = (float)pk.h[3];
        float* op = out + (size_t)n * T * HID + (size_t)t * HID + blk * 4;
        st64c(op, o0.q);
        st64c(op + 2, o1.q);
      }
    }

    if (p < NP - 1) {
      // ARRIVE drains wave0's stores (tid0 is wave0), fires the one-way
      // arrival add, then the release-detection shadow is filled with
      // hh-GEMM(p+1): operand = output of slot p-1 (already visible), and
      // it's the SAME plane pIh just read -> L2-hot.
      ARRIVE();
      const f16* pSh = L ? l0P[wp] : l1P[rp];
      a0 = fz; a1 = fz; a2 = fz; a3 = fz;
      gemmK256(pSh, ((L ^ 1) * 16 + l15) * AVEC + 128 + wave * 32 + quad);
      // leader inv AFTER shadow reads: clears stale lines for next slot's
      // plane without evicting this slot's hot lines
      if (is_leader) asm volatile("buffer_inv sc1" ::: "memory");
    } else {
      asm volatile("s_waitcnt vmcnt(0)" ::: "memory");
    }
  }
}

extern "C" void kernel_launch(void* const* d_in, const int* in_sizes, int n_in,
                              void* d_out, int out_size, void* d_ws, size_t ws_size,
                              hipStream_t stream) {
  const float* x0  = (const float*)d_in[0];
  const float* h0  = (const float*)d_in[1];
  const float* c0  = (const float*)d_in[2];
  const float* Wih = (const float*)d_in[3];
  const float* Whh = (const float*)d_in[4];
  const float* bih = (const float*)d_in[5];
  const float* bhh = (const float*)d_in[6];
  const int* lenp  = (const int*)d_in[7];
  float* out = (float*)d_out;

  int* bar    = (int*)d_ws;
  f16* planes = (f16*)((char*)d_ws + 16384);   // 5 planes x 128 KB

  hipFuncSetAttribute((const void*)lstm_kernel,
                      hipFuncAttributeMaxDynamicSharedMemorySize, LDS_BYTES);

  bar_init<<<1, 1024, 0, stream>>>(bar);

  void* args[] = {&x0, &h0, &c0, &Wih, &Whh, &bih, &bhh, &lenp, &out, &bar, &planes};
  hipLaunchCooperativeKernel((void*)lstm_kernel, dim3(NBLK), dim3(NTHR),
                             args, LDS_BYTES, stream);
}

// Round 7
// 2517.158 us; speedup vs baseline: 1.1068x; 1.1068x over previous
//
#include <hip/hip_runtime.h>
#include <hip/hip_fp16.h>

#define HID   1024
#define NBAT  64
#define NBLK  256
#define NTHR  256
#define AROW  2056              // 2048 + 8 pad (f16 elems)
#define AVEC  257               // AROW/8
#define PLANE 65536             // f16 elems per activation plane: [256 blk][64 n][4 j]

typedef _Float16 f16;
typedef unsigned long long u64;
typedef __attribute__((ext_vector_type(8))) _Float16 f16x8;
typedef __attribute__((ext_vector_type(4))) float f32x4;

// LDS layout (bytes) -- R1's exact layout
#define A_BYTES   (2 * 16 * AROW * 2)    // 131584
#define SCR_OFF   A_BYTES                // f32 [4 kg][16 rows][64 batch] = 16384
#define C_OFF     (SCR_OFF + 16384)      // f32 [2][4][64] = 2048
#define BIAS_OFF  (C_OFF + 2048)         // f32 [2][16] = 128
#define HS_OFF    (BIAS_OFF + 128)       // f16 [64][4] = 512
#define LDS_BYTES (HS_OFF + 512)         // 150656 < 160 KiB

// barrier ints (256B-spaced): leaf i: bar[64*i] i<16 | root: bar[64*16] (unused)
// release flag i: bar[64*(17+i)] i<16 | xcd elect x: bar[64*(33+x)] x<8
#define BAR_INTS  (64 * 41)

#define COMPILER_FENCE() asm volatile("" ::: "memory")

__device__ __forceinline__ float sigm(float x) { return 1.f / (1.f + __expf(-x)); }
__device__ __forceinline__ float tanh_f(float x) {
  float xc = fminf(fmaxf(x, -10.f), 10.f);
  float e = __expf(2.f * xc);
  return (e - 1.f) / (e + 1.f);
}

// write-through store (coherent via MALL)
__device__ __forceinline__ void st64c(void* p, u64 v) {
  __hip_atomic_store((u64*)p, v, __ATOMIC_RELAXED, __HIP_MEMORY_SCOPE_AGENT);
}

__global__ void bar_init(int* bar) {
  int i = threadIdx.x;
  #pragma unroll
  for (int k = 0; k < 3; ++k) {
    int idx = i + k * 1024;
    if (idx < BAR_INTS) bar[idx] = 0;
  }
}

// R7 = R1's proven dataflow (inline-load GEMMs, NO operand-register carry
// across sync points -- the R3-R6 poison pattern is fully excised) with a
// restructured barrier:
//  * arrivals are fire-and-forget one-way leaf adds (no RMW round-trip on
//    any worker's critical path);
//  * block 0 tid0 is the sole RELEASER: during the shadow it sweep-polls
//    the 16 leaf counters (16 pipelined RMWs = ~1 MALL RT per sweep, one
//    poller per line) and fires the 16 release flags when sum>=256*epoch.
//    Monotone counters + blocks cannot arrive for e+1 before release(e)
//    => partial-snapshot sum can never falsely release.
//  * shadow hh-GEMM runs on waves 1-3 (K-chunks 11/11/10); the ew sum over
//    all 4 scr slots is split-agnostic. Wave0 is free post-ARRIVE: it does
//    out-stores (no remote reader -> moved out of the pre-arrival drain),
//    leader buffer_inv (no longer delays shadow GEMM), and block0 release.
__global__ __launch_bounds__(NTHR, 1) void lstm_kernel(
    const float* __restrict__ x0, const float* __restrict__ h0,
    const float* __restrict__ c0, const float* __restrict__ Wih,
    const float* __restrict__ Whh, const float* __restrict__ bih,
    const float* __restrict__ bhh, const int* __restrict__ lenp,
    float* __restrict__ out, int* __restrict__ bar, f16* __restrict__ planes)
{
  extern __shared__ char smem[];
  f16*   Alds  = (f16*)smem;
  float* scr   = (float*)(smem + SCR_OFF);
  float* cS    = (float*)(smem + C_OFF);
  float* biasS = (float*)(smem + BIAS_OFF);
  f16*   hS    = (f16*)(smem + HS_OFF);     // [n][j] transpose buffer

  const int tid  = threadIdx.x;
  const int blk  = blockIdx.x;
  const int wave = tid >> 6;
  const int lane = tid & 63;
  const int quad = lane >> 4;
  const int l15  = lane & 15;
  const int T    = *lenp;

  f16* l0P[2] = { planes,             planes + PLANE };
  f16* l1P[2] = { planes + 2 * PLANE, planes + 3 * PLANE };
  f16* xP     =   planes + 4 * PLANE;

  int* leaf  = bar + 64 * (blk & 15);
  int* relme = bar + 64 * (17 + (blk & 15));

  // ---- physical XCD id + one-time leader election ----
  unsigned xcc;
  asm volatile("s_getreg_b32 %0, hwreg(HW_REG_XCC_ID)" : "=s"(xcc));
  xcc &= 7;
  int is_leader = 0;
  if (tid == 0) {
    int p = __hip_atomic_fetch_add(bar + 64 * (33 + xcc), 1, __ATOMIC_RELAXED,
                                   __HIP_MEMORY_SCOPE_AGENT);
    is_leader = (p == 0);
  }

  // ---- stage weights (f32 -> f16) into LDS ----
  {
    int r    = tid >> 2;
    int part = tid & 3;
    int l    = r >> 5;
    int m    = (r >> 1) & 15;
    int half = r & 1;
    int g    = m >> 2, j = m & 3;
    size_t grow = (size_t)g * HID + blk * 4 + j;
    const float* srcW = (half ? Whh : Wih) + ((size_t)l * 4 * HID + grow) * HID + part * 256;
    f16x8* dst = (f16x8*)(Alds + (size_t)(l * 16 + m) * AROW + half * HID + part * 256);
    const float4* s4 = (const float4*)srcW;
    #pragma unroll 4
    for (int i = 0; i < 32; ++i) {
      float4 w0 = s4[2 * i], w1 = s4[2 * i + 1];
      f16x8 o = {(f16)w0.x, (f16)w0.y, (f16)w0.z, (f16)w0.w,
                 (f16)w1.x, (f16)w1.y, (f16)w1.z, (f16)w1.w};
      dst[i] = o;
    }
  }
  // ---- biases ----
  if (tid < 32) {
    int l = tid >> 4, m = tid & 15;
    int g = m >> 2, j = m & 3;
    size_t row = (size_t)g * HID + blk * 4 + j;
    biasS[l * 16 + m] = bih[(size_t)l * 4 * HID + row] + bhh[(size_t)l * 4 * HID + row];
  }
  // ---- c state (LDS, CU-local), R1 layout ----
  {
    int j = tid >> 6, n = tid & 63;
    #pragma unroll
    for (int l = 0; l < 2; ++l)
      cS[l * 256 + j * 64 + n] =
          c0[(size_t)l * NBAT * HID + (size_t)n * HID + blk * 4 + j];
  }
  // ---- h0 -> parity-1 planes (block-contiguous, 8B/lane) ----
  if (tid < 128) {
    int l = tid >> 6, n = tid & 63;
    const float* hp = h0 + (size_t)l * NBAT * HID + (size_t)n * HID + blk * 4;
    union { u64 q; f16 h[4]; } pk;
    pk.h[0] = (f16)hp[0]; pk.h[1] = (f16)hp[1]; pk.h[2] = (f16)hp[2]; pk.h[3] = (f16)hp[3];
    st64c((l == 0 ? l0P[1] : l1P[1]) + blk * 256 + n * 4, pk.q);
  }
  // ---- x0 -> xP (each block stages its own 4-unit slot) ----
  if (tid < 64) {
    int n = tid;
    const float* xp = x0 + (size_t)n * HID + blk * 4;
    union { u64 q; f16 h[4]; } pk;
    pk.h[0] = (f16)xp[0]; pk.h[1] = (f16)xp[1]; pk.h[2] = (f16)xp[2]; pk.h[3] = (f16)xp[3];
    st64c(xP + blk * 256 + n * 4, pk.q);
  }
  // one-time safety inv (poison/stale lines) before first arrival
  if (wave == 0) asm volatile("buffer_inv sc1" ::: "memory");

  // ---- barrier: one-way arrivals + block0 releaser + release-flag polls ----
  int epoch = 1;
  int self_rel = 0;

  #define ARRIVE()                                                              \
    do {                                                                        \
      asm volatile("s_waitcnt vmcnt(0)" ::: "memory");                          \
      if (tid == 0)                                                             \
        (void)__hip_atomic_fetch_add(leaf, 1, __ATOMIC_RELAXED,                 \
                                     __HIP_MEMORY_SCOPE_AGENT);                 \
    } while (0)

  #define RELEASE_DUTY()                                                        \
    do {                                                                        \
      if (blk == 0 && tid == 0) {                                               \
        for (;;) {                                                              \
          int s_ = 0;                                                           \
          _Pragma("unroll")                                                     \
          for (int i_ = 0; i_ < 16; ++i_)                                       \
            s_ += __hip_atomic_fetch_add(bar + 64 * i_, 0, __ATOMIC_RELAXED,    \
                                         __HIP_MEMORY_SCOPE_AGENT);             \
          if (s_ >= 256 * epoch) break;                                         \
          __builtin_amdgcn_s_sleep(1);                                          \
        }                                                                       \
        _Pragma("unroll")                                                       \
        for (int i_ = 0; i_ < 16; ++i_)                                         \
          __hip_atomic_fetch_add(bar + 64 * (17 + i_), 1, __ATOMIC_RELAXED,     \
                                 __HIP_MEMORY_SCOPE_AGENT);                     \
        self_rel = 1;                                                           \
      }                                                                         \
    } while (0)

  #define WAIT_REL()                                                            \
    do {                                                                        \
      if (tid == 0 && !self_rel) {                                              \
        while (__hip_atomic_fetch_add(relme, 0, __ATOMIC_RELAXED,               \
                                      __HIP_MEMORY_SCOPE_AGENT) < epoch)        \
          __builtin_amdgcn_s_sleep(1);                                          \
      }                                                                         \
      self_rel = 0;                                                             \
      epoch++;                                                                  \
      __syncthreads();                                                          \
      COMPILER_FENCE();                                                         \
    } while (0)

  // initial barrier: every wave drains its own staging stores, converges,
  // then arrival + release + wait
  asm volatile("s_waitcnt vmcnt(0)" ::: "memory");
  __syncthreads();
  ARRIVE();
  RELEASE_DUTY();
  WAIT_REL();

  const f16x8* Av = (const f16x8*)Alds;
  const f32x4 fz = {0.f, 0.f, 0.f, 0.f};
  f32x4 a0, a1, a2, a3;

  // shadow hh K-chunk range for this wave: waves 1-3 split 32 chunks
  const int cb = (wave == 1) ? 0 : (wave == 2) ? 11 : (wave == 3) ? 22 : 0;
  const int ce = (wave == 1) ? 11 : (wave == 2) ? 22 : (wave == 3) ? 32 : 0;

  // R1-exact ih GEMM: this wave's K=256 slice, loads consumed inline
  auto gemmK256 = [&](const f16* psrc, int aoff) {
    const f16* p0 = psrc + (wave * 64 + quad * 2) * 256 + l15 * 4;
    #pragma unroll
    for (int kk = 0; kk < 8; ++kk) {
      f16x8 af = Av[aoff + kk * 4];
      const f16* k0 = p0 + kk * 2048;
      union { u64 q[2]; f16x8 v; } b0, b1, b2, b3;
      b0.q[0] = *(const u64*)(k0 +   0); b0.q[1] = *(const u64*)(k0 + 256);
      b1.q[0] = *(const u64*)(k0 +  64); b1.q[1] = *(const u64*)(k0 + 320);
      b2.q[0] = *(const u64*)(k0 + 128); b2.q[1] = *(const u64*)(k0 + 384);
      b3.q[0] = *(const u64*)(k0 + 192); b3.q[1] = *(const u64*)(k0 + 448);
      a0 = __builtin_amdgcn_mfma_f32_16x16x32_f16(af, b0.v, a0, 0, 0, 0);
      a1 = __builtin_amdgcn_mfma_f32_16x16x32_f16(af, b1.v, a1, 0, 0, 0);
      a2 = __builtin_amdgcn_mfma_f32_16x16x32_f16(af, b2.v, a2, 0, 0, 0);
      a3 = __builtin_amdgcn_mfma_f32_16x16x32_f16(af, b3.v, a3, 0, 0, 0);
    }
  };
  // ranged GEMM (shadow hh, waves 1-3): same addressing with global chunk c
  // (c = wave*8+kk in gemmK256 terms), loads consumed inline
  auto gemmRange = [&](const f16* psrc, int rowbase) {
    for (int c = cb; c < ce; ++c) {
      f16x8 af = Av[rowbase + quad + c * 4];
      const f16* k0 = psrc + (c * 8 + quad * 2) * 256 + l15 * 4;
      union { u64 q[2]; f16x8 v; } b0, b1, b2, b3;
      b0.q[0] = *(const u64*)(k0 +   0); b0.q[1] = *(const u64*)(k0 + 256);
      b1.q[0] = *(const u64*)(k0 +  64); b1.q[1] = *(const u64*)(k0 + 320);
      b2.q[0] = *(const u64*)(k0 + 128); b2.q[1] = *(const u64*)(k0 + 384);
      b3.q[0] = *(const u64*)(k0 + 192); b3.q[1] = *(const u64*)(k0 + 448);
      a0 = __builtin_amdgcn_mfma_f32_16x16x32_f16(af, b0.v, a0, 0, 0, 0);
      a1 = __builtin_amdgcn_mfma_f32_16x16x32_f16(af, b1.v, a1, 0, 0, 0);
      a2 = __builtin_amdgcn_mfma_f32_16x16x32_f16(af, b2.v, a2, 0, 0, 0);
      a3 = __builtin_amdgcn_mfma_f32_16x16x32_f16(af, b3.v, a3, 0, 0, 0);
    }
  };

  // ---- prologue: hh(t=0,l=0) from the initial h0 plane (waves 1-3) ----
  a0 = fz; a1 = fz; a2 = fz; a3 = fz;
  gemmRange(l0P[1], (0 * 16 + l15) * AVEC + 128);

  const int NP = 2 * T;
  #pragma unroll 1
  for (int p = 0; p < NP; ++p) {
    const int L = p & 1, t = p >> 1, wp = t & 1, rp = wp ^ 1;
    if (p) WAIT_REL();

    // ---- ih-GEMM(p): all 4 waves, operand written at slot p-1 ----
    const f16* pIh = L ? l0P[wp] : (t ? l1P[rp] : xP);
    gemmK256(pIh, (L * 16 + l15) * AVEC + wave * 32 + quad);

    // ---- partials (hh(p)+ih(p)) to LDS scratch ----
    float* sc = scr + wave * 1024;
    #pragma unroll
    for (int r = 0; r < 4; ++r) {
      int base = (quad * 4 + r) * 64 + l15;
      sc[base +  0] = a0[r];
      sc[base + 16] = a1[r];
      sc[base + 32] = a2[r];
      sc[base + 48] = a3[r];
    }
    __syncthreads();

    // ---- elementwise (R1 mapping): thread = (unit j, batch n) ----
    {
      int j = tid >> 6, n = tid & 63;
      float gate[4];
      #pragma unroll
      for (int g = 0; g < 4; ++g) {
        int b0i = (g * 4 + j) * 64 + n;
        gate[g] = scr[b0i] + scr[1024 + b0i] + scr[2048 + b0i] + scr[3072 + b0i]
                + biasS[L * 16 + g * 4 + j];
      }
      float cold = cS[L * 256 + j * 64 + n];
      float cn = sigm(gate[1]) * cold + sigm(gate[0]) * tanh_f(gate[2]);
      float hn = sigm(gate[3]) * tanh_f(cn);
      cS[L * 256 + j * 64 + n] = cn;
      hS[n * 4 + j] = (f16)hn;
    }
    __syncthreads();

    // ---- plane h-store (pre-arrival, must drain): wave0, 512B chunk ----
    if (tid < 64) {
      int n = tid;
      u64 pq = *(const u64*)(hS + n * 4);
      st64c((L == 0 ? l0P[wp] : l1P[wp]) + blk * 256 + n * 4, pq);
    }

    if (p < NP - 1) {
      // ARRIVE: wave0 drains its plane store, tid0 fires one-way arrival.
      ARRIVE();
      // out-store (no remote reader) moved POST-arrival: re-read hS (LDS,
      // block-local; next overwrite is after the next WAIT barrier).
      if (L == 1 && tid < 64) {
        int n = tid;
        union { u64 q; f16 h[4]; } pk;
        pk.q = *(const u64*)(hS + n * 4);
        union { u64 q; float f[2]; } o0, o1;
        o0.f[0] = (float)pk.h[0]; o0.f[1] = (float)pk.h[1];
        o1.f[0] = (float)pk.h[2]; o1.f[1] = (float)pk.h[3];
        float* op = out + (size_t)n * T * HID + (size_t)t * HID + blk * 4;
        st64c(op, o0.q);
        st64c(op + 2, o1.q);
      }
      // leader inv early (wave0): value-safe (MALL holds truth; evicted
      // shadow lines refetch, hidden under release). Completes long before
      // release fires.
      if (is_leader) asm volatile("buffer_inv sc1" ::: "memory");
      // shadow: hh(p+1) on waves 1-3, inline loads (R1-proven pattern);
      // same plane as pIh (p==0: l1P[rp]==l1P[1] handles h0-L1 naturally)
      a0 = fz; a1 = fz; a2 = fz; a3 = fz;
      const f16* pSh = L ? l0P[wp] : l1P[rp];
      gemmRange(pSh, ((L ^ 1) * 16 + l15) * AVEC + 128);
      // block0 tid0 (wave0, free): sweep leaves, fire release flags
      RELEASE_DUTY();
    } else {
      // last slot: out-store then final drain
      if (tid < 64) {
        int n = tid;
        union { u64 q; f16 h[4]; } pk;
        pk.q = *(const u64*)(hS + n * 4);
        union { u64 q; float f[2]; } o0, o1;
        o0.f[0] = (float)pk.h[0]; o0.f[1] = (float)pk.h[1];
        o1.f[0] = (float)pk.h[2]; o1.f[1] = (float)pk.h[3];
        float* op = out + (size_t)n * T * HID + (size_t)t * HID + blk * 4;
        st64c(op, o0.q);
        st64c(op + 2, o1.q);
      }
      asm volatile("s_waitcnt vmcnt(0)" ::: "memory");
    }
  }
}

extern "C" void kernel_launch(void* const* d_in, const int* in_sizes, int n_in,
                              void* d_out, int out_size, void* d_ws, size_t ws_size,
                              hipStream_t stream) {
  const float* x0  = (const float*)d_in[0];
  const float* h0  = (const float*)d_in[1];
  const float* c0  = (const float*)d_in[2];
  const float* Wih = (const float*)d_in[3];
  const float* Whh = (const float*)d_in[4];
  const float* bih = (const float*)d_in[5];
  const float* bhh = (const float*)d_in[6];
  const int* lenp  = (const int*)d_in[7];
  float* out = (float*)d_out;

  int* bar    = (int*)d_ws;
  f16* planes = (f16*)((char*)d_ws + 16384);   // 5 planes x 128 KB

  hipFuncSetAttribute((const void*)lstm_kernel,
                      hipFuncAttributeMaxDynamicSharedMemorySize, LDS_BYTES);

  bar_init<<<1, 1024, 0, stream>>>(bar);

  void* args[] = {&x0, &h0, &c0, &Wih, &Whh, &bih, &bhh, &lenp, &out, &bar, &planes};
  hipLaunchCooperativeKernel((void*)lstm_kernel, dim3(NBLK), dim3(NTHR),
                             args, LDS_BYTES, stream);
}

// Round 8
// 1649.542 us; speedup vs baseline: 1.6889x; 1.5260x over previous
//
#include <hip/hip_runtime.h>
#include <hip/hip_fp16.h>

#define HID   1024
#define NBAT  64
#define NBLK  256
#define NTHR  256
#define AROW  2056              // 2048 + 8 pad (f16 elems)
#define AVEC  257               // AROW/8
#define PLANE 65536             // f16 elems per activation plane: [256 blk][64 n][4 j]

typedef _Float16 f16;
typedef unsigned long long u64;
typedef __attribute__((ext_vector_type(8))) _Float16 f16x8;
typedef __attribute__((ext_vector_type(4))) float f32x4;

// LDS layout (bytes)
#define A_BYTES   (2 * 16 * AROW * 2)    // 131584
#define SCR_OFF   A_BYTES                // f32 [4 kg][16 rows][64 batch] = 16384
#define C_OFF     (SCR_OFF + 16384)      // f32 [2][4][64] = 2048
#define BIAS_OFF  (C_OFF + 2048)         // f32 [2][16] = 128
#define HS_OFF    (BIAS_OFF + 128)       // f16 [64][4] = 512
#define LDS_BYTES (HS_OFF + 512)         // 150656 < 160 KiB

// barrier ints (256B-spaced): leaf i: bar[64*i] i<16 | root: bar[64*16] (unused)
// release flag i: bar[64*(17+i)] i<16 | xcd elect x: bar[64*(33+x)] x<8
#define BAR_INTS  (64 * 41)

#define COMPILER_FENCE() asm volatile("" ::: "memory")

__device__ __forceinline__ float sigm(float x) { return 1.f / (1.f + __expf(-x)); }
__device__ __forceinline__ float tanh_f(float x) {
  float xc = fminf(fmaxf(x, -10.f), 10.f);
  float e = __expf(2.f * xc);
  return (e - 1.f) / (e + 1.f);
}

// write-through store (coherent via MALL)
__device__ __forceinline__ void st64c(void* p, u64 v) {
  __hip_atomic_store((u64*)p, v, __ATOMIC_RELAXED, __HIP_MEMORY_SCOPE_AGENT);
}

__global__ void bar_init(int* bar) {
  int i = threadIdx.x;
  #pragma unroll
  for (int k = 0; k < 3; ++k) {
    int idx = i + k * 1024;
    if (idx < BAR_INTS) bar[idx] = 0;
  }
}

// R8 = R1 (proven 1600us: inline-load GEMMs, 4-wave shadow hh, late inv,
// wave0 h+out store) with ONE barrier change: the root hop is removed.
// Each leaf's finisher (prev==16*epoch-1 on its leaf) adds +1 directly to
// ALL 16 release flags (one-way pipelined RMWs); pollers wait for
// relme >= 16*epoch. All-leaves-done <=> flag count reaches 16*epoch;
// cumulative monotone count + release(e) gating arrivals for e+1 => no
// false release. Saves one full MALL round-trip per slot vs R1's
// leaf->root->release chain. Contention per flag line: 16 finisher adds +
// 16 pollers per epoch (R2's collapse was 256 pollers/line; this is fine).
// R3-R6 lesson kept: NO operand-register carry across sync points; all
// MFMA B-operands are loaded inline in the consuming phase.
__global__ __launch_bounds__(NTHR, 1) void lstm_kernel(
    const float* __restrict__ x0, const float* __restrict__ h0,
    const float* __restrict__ c0, const float* __restrict__ Wih,
    const float* __restrict__ Whh, const float* __restrict__ bih,
    const float* __restrict__ bhh, const int* __restrict__ lenp,
    float* __restrict__ out, int* __restrict__ bar, f16* __restrict__ planes)
{
  extern __shared__ char smem[];
  f16*   Alds  = (f16*)smem;
  float* scr   = (float*)(smem + SCR_OFF);
  float* cS    = (float*)(smem + C_OFF);
  float* biasS = (float*)(smem + BIAS_OFF);
  f16*   hS    = (f16*)(smem + HS_OFF);     // [n][j] transpose buffer

  const int tid  = threadIdx.x;
  const int blk  = blockIdx.x;
  const int wave = tid >> 6;
  const int lane = tid & 63;
  const int quad = lane >> 4;
  const int l15  = lane & 15;
  const int T    = *lenp;

  f16* l0P[2] = { planes,             planes + PLANE };
  f16* l1P[2] = { planes + 2 * PLANE, planes + 3 * PLANE };
  f16* xP     =   planes + 4 * PLANE;

  const int leafid = blk & 15;
  int* leaf  = bar + 64 * leafid;
  int* relme = bar + 64 * (17 + leafid);

  // ---- physical XCD id + one-time leader election ----
  unsigned xcc;
  asm volatile("s_getreg_b32 %0, hwreg(HW_REG_XCC_ID)" : "=s"(xcc));
  xcc &= 7;
  int is_leader = 0;
  if (tid == 0) {
    int p = __hip_atomic_fetch_add(bar + 64 * (33 + xcc), 1, __ATOMIC_RELAXED,
                                   __HIP_MEMORY_SCOPE_AGENT);
    is_leader = (p == 0);
  }

  // ---- stage weights (f32 -> f16) into LDS ----
  {
    int r    = tid >> 2;
    int part = tid & 3;
    int l    = r >> 5;
    int m    = (r >> 1) & 15;
    int half = r & 1;
    int g    = m >> 2, j = m & 3;
    size_t grow = (size_t)g * HID + blk * 4 + j;
    const float* srcW = (half ? Whh : Wih) + ((size_t)l * 4 * HID + grow) * HID + part * 256;
    f16x8* dst = (f16x8*)(Alds + (size_t)(l * 16 + m) * AROW + half * HID + part * 256);
    const float4* s4 = (const float4*)srcW;
    #pragma unroll 4
    for (int i = 0; i < 32; ++i) {
      float4 w0 = s4[2 * i], w1 = s4[2 * i + 1];
      f16x8 o = {(f16)w0.x, (f16)w0.y, (f16)w0.z, (f16)w0.w,
                 (f16)w1.x, (f16)w1.y, (f16)w1.z, (f16)w1.w};
      dst[i] = o;
    }
  }
  // ---- biases ----
  if (tid < 32) {
    int l = tid >> 4, m = tid & 15;
    int g = m >> 2, j = m & 3;
    size_t row = (size_t)g * HID + blk * 4 + j;
    biasS[l * 16 + m] = bih[(size_t)l * 4 * HID + row] + bhh[(size_t)l * 4 * HID + row];
  }
  // ---- c state (LDS, CU-local) ----
  {
    int j = tid >> 6, n = tid & 63;
    #pragma unroll
    for (int l = 0; l < 2; ++l)
      cS[l * 256 + j * 64 + n] =
          c0[(size_t)l * NBAT * HID + (size_t)n * HID + blk * 4 + j];
  }
  // ---- h0 -> parity-1 planes (block-contiguous, 8B/lane) ----
  if (tid < 128) {
    int l = tid >> 6, n = tid & 63;
    const float* hp = h0 + (size_t)l * NBAT * HID + (size_t)n * HID + blk * 4;
    union { u64 q; f16 h[4]; } pk;
    pk.h[0] = (f16)hp[0]; pk.h[1] = (f16)hp[1]; pk.h[2] = (f16)hp[2]; pk.h[3] = (f16)hp[3];
    st64c((l == 0 ? l0P[1] : l1P[1]) + blk * 256 + n * 4, pk.q);
  }
  // ---- x0 -> xP (each block stages its own 4-unit slot) ----
  if (tid < 64) {
    int n = tid;
    const float* xp = x0 + (size_t)n * HID + blk * 4;
    union { u64 q; f16 h[4]; } pk;
    pk.h[0] = (f16)xp[0]; pk.h[1] = (f16)xp[1]; pk.h[2] = (f16)xp[2]; pk.h[3] = (f16)xp[3];
    st64c(xP + blk * 256 + n * 4, pk.q);
  }
  // one-time safety inv (poison/stale lines) before first arrival
  if (wave == 0) asm volatile("buffer_inv sc1" ::: "memory");

  // ---- split grid barrier: flattened push cascade (no root hop) ----
  int epoch = 1;

  #define ARRIVE()                                                              \
    do {                                                                        \
      asm volatile("s_waitcnt vmcnt(0)" ::: "memory");                          \
      if (tid == 0) {                                                           \
        int prev = __hip_atomic_fetch_add(leaf, 1, __ATOMIC_RELAXED,            \
                                          __HIP_MEMORY_SCOPE_AGENT);            \
        if (prev == 16 * epoch - 1) {                                           \
          _Pragma("unroll")                                                     \
          for (int i_ = 0; i_ < 16; ++i_)                                       \
            (void)__hip_atomic_fetch_add(bar + 64 * (17 + i_), 1,               \
                                         __ATOMIC_RELAXED,                      \
                                         __HIP_MEMORY_SCOPE_AGENT);             \
        }                                                                       \
      }                                                                         \
    } while (0)

  #define WAIT_REL()                                                            \
    do {                                                                        \
      if (tid == 0) {                                                           \
        while (__hip_atomic_fetch_add(relme, 0, __ATOMIC_RELAXED,               \
                                      __HIP_MEMORY_SCOPE_AGENT) < 16 * epoch)   \
          __builtin_amdgcn_s_sleep(1);                                          \
      }                                                                         \
      epoch++;                                                                  \
      __syncthreads();                                                          \
      COMPILER_FENCE();                                                         \
    } while (0)

  // initial barrier: staging used waves 0-1, so every wave drains its own
  // stores, converges, then tid0 arrives
  asm volatile("s_waitcnt vmcnt(0)" ::: "memory");
  __syncthreads();
  ARRIVE();
  WAIT_REL();

  const f16x8* Av = (const f16x8*)Alds;
  const f32x4 fz = {0.f, 0.f, 0.f, 0.f};
  f32x4 a0, a1, a2, a3;

  // one K=1024 GEMM over a full activation plane; wave w covers plane units
  // [w*256, w*256+256). A-frag chunk aoff walks the matching K-slice.
  // Loads consumed INLINE (R3-R6 lesson: no register carry across syncs).
  auto gemmK256 = [&](const f16* psrc, int aoff) {
    const f16* p0 = psrc + (wave * 64 + quad * 2) * 256 + l15 * 4;
    #pragma unroll
    for (int kk = 0; kk < 8; ++kk) {
      f16x8 af = Av[aoff + kk * 4];
      const f16* k0 = p0 + kk * 2048;
      union { u64 q[2]; f16x8 v; } b0, b1, b2, b3;
      b0.q[0] = *(const u64*)(k0 +   0); b0.q[1] = *(const u64*)(k0 + 256);
      b1.q[0] = *(const u64*)(k0 +  64); b1.q[1] = *(const u64*)(k0 + 320);
      b2.q[0] = *(const u64*)(k0 + 128); b2.q[1] = *(const u64*)(k0 + 384);
      b3.q[0] = *(const u64*)(k0 + 192); b3.q[1] = *(const u64*)(k0 + 448);
      a0 = __builtin_amdgcn_mfma_f32_16x16x32_f16(af, b0.v, a0, 0, 0, 0);
      a1 = __builtin_amdgcn_mfma_f32_16x16x32_f16(af, b1.v, a1, 0, 0, 0);
      a2 = __builtin_amdgcn_mfma_f32_16x16x32_f16(af, b2.v, a2, 0, 0, 0);
      a3 = __builtin_amdgcn_mfma_f32_16x16x32_f16(af, b3.v, a3, 0, 0, 0);
    }
  };

  // ---- prologue: hh(t=0,l=0) from the initial h0 plane (parity 1) ----
  a0 = fz; a1 = fz; a2 = fz; a3 = fz;
  gemmK256(l0P[1], (0 * 16 + l15) * AVEC + 128 + wave * 32 + quad);

  const int NP = 2 * T;
  #pragma unroll 1
  for (int p = 0; p < NP; ++p) {
    const int L = p & 1, t = p >> 1, wp = t & 1, rp = wp ^ 1;
    if (p) WAIT_REL();

    // ---- ih-GEMM(p): operand written at slot p-1, visible per WAIT ----
    const f16* pIh = L ? l0P[wp] : (t ? l1P[rp] : xP);
    gemmK256(pIh, (L * 16 + l15) * AVEC + wave * 32 + quad);

    // ---- partials (hh(p)+ih(p)) to LDS scratch ----
    float* sc = scr + wave * 1024;
    #pragma unroll
    for (int r = 0; r < 4; ++r) {
      int base = (quad * 4 + r) * 64 + l15;
      sc[base +  0] = a0[r];
      sc[base + 16] = a1[r];
      sc[base + 32] = a2[r];
      sc[base + 48] = a3[r];
    }
    __syncthreads();

    // ---- elementwise: thread = (unit j, batch n) ----
    {
      int j = tid >> 6, n = tid & 63;
      float gate[4];
      #pragma unroll
      for (int g = 0; g < 4; ++g) {
        int b0i = (g * 4 + j) * 64 + n;
        gate[g] = scr[b0i] + scr[1024 + b0i] + scr[2048 + b0i] + scr[3072 + b0i]
                + biasS[L * 16 + g * 4 + j];
      }
      float cold = cS[L * 256 + j * 64 + n];
      float cn = sigm(gate[1]) * cold + sigm(gate[0]) * tanh_f(gate[2]);
      float hn = sigm(gate[3]) * tanh_f(cn);
      cS[L * 256 + j * 64 + n] = cn;
      hS[n * 4 + j] = (f16)hn;
    }
    __syncthreads();

    // ---- h store: ONE contiguous 512B chunk per block (+ out on L==1) ----
    if (tid < 64) {
      int n = tid;
      union { u64 q; f16 h[4]; } pk;
      pk.q = *(const u64*)(hS + n * 4);
      st64c((L == 0 ? l0P[wp] : l1P[wp]) + blk * 256 + n * 4, pk.q);
      if (L == 1) {
        union { u64 q; float f[2]; } o0, o1;
        o0.f[0] = (float)pk.h[0]; o0.f[1] = (float)pk.h[1];
        o1.f[0] = (float)pk.h[2]; o1.f[1] = (float)pk.h[3];
        float* op = out + (size_t)n * T * HID + (size_t)t * HID + blk * 4;
        st64c(op, o0.q);
        st64c(op + 2, o1.q);
      }
    }

    if (p < NP - 1) {
      // ARRIVE drains wave0's stores (tid0 is wave0), fires arrival (and,
      // for a leaf finisher, the 16 one-way release adds). Then the
      // release-propagation shadow is filled with hh-GEMM(p+1): operand =
      // output of slot p-1 (already visible), SAME plane as ih(p) -> L2-hot.
      ARRIVE();
      const f16* pSh = L ? l0P[wp] : l1P[rp];
      a0 = fz; a1 = fz; a2 = fz; a3 = fz;
      gemmK256(pSh, ((L ^ 1) * 16 + l15) * AVEC + 128 + wave * 32 + quad);
      // leader inv AFTER shadow reads: clears stale lines for next slot's
      // plane without evicting this slot's hot lines
      if (is_leader) asm volatile("buffer_inv sc1" ::: "memory");
    } else {
      asm volatile("s_waitcnt vmcnt(0)" ::: "memory");
    }
  }
}

extern "C" void kernel_launch(void* const* d_in, const int* in_sizes, int n_in,
                              void* d_out, int out_size, void* d_ws, size_t ws_size,
                              hipStream_t stream) {
  const float* x0  = (const float*)d_in[0];
  const float* h0  = (const float*)d_in[1];
  const float* c0  = (const float*)d_in[2];
  const float* Wih = (const float*)d_in[3];
  const float* Whh = (const float*)d_in[4];
  const float* bih = (const float*)d_in[5];
  const float* bhh = (const float*)d_in[6];
  const int* lenp  = (const int*)d_in[7];
  float* out = (float*)d_out;

  int* bar    = (int*)d_ws;
  f16* planes = (f16*)((char*)d_ws + 16384);   // 5 planes x 128 KB

  hipFuncSetAttribute((const void*)lstm_kernel,
                      hipFuncAttributeMaxDynamicSharedMemorySize, LDS_BYTES);

  bar_init<<<1, 1024, 0, stream>>>(bar);

  void* args[] = {&x0, &h0, &c0, &Wih, &Whh, &bih, &bhh, &lenp, &out, &bar, &planes};
  hipLaunchCooperativeKernel((void*)lstm_kernel, dim3(NBLK), dim3(NTHR),
                             args, LDS_BYTES, stream);
}

// Round 9
// 1644.362 us; speedup vs baseline: 1.6942x; 1.0032x over previous
//
#include <hip/hip_runtime.h>
#include <hip/hip_fp16.h>

#define HID   1024
#define NBAT  64
#define NBLK  256
#define NTHR  256
#define AROW  2056              // 2048 + 8 pad (f16 elems)
#define AVEC  257               // AROW/8
#define PLANE 65536             // f16 elems per activation plane: [256 blk][64 n][4 j]

typedef _Float16 f16;
typedef unsigned long long u64;
typedef __attribute__((ext_vector_type(8))) _Float16 f16x8;
typedef __attribute__((ext_vector_type(4))) float f32x4;

// LDS layout (bytes)
#define A_BYTES   (2 * 16 * AROW * 2)    // 131584
#define SCR_OFF   A_BYTES                // f32 [4 kg][16 rows][64 batch] = 16384
#define C_OFF     (SCR_OFF + 16384)      // f32 [2][4][64] = 2048
#define BIAS_OFF  (C_OFF + 2048)         // f32 [2][16] = 128
#define HS_OFF    (BIAS_OFF + 128)       // f16 [64][4] = 512
#define LDS_BYTES (HS_OFF + 512)         // 150656 < 160 KiB

// barrier ints (256B-spaced): leaf i: bar[64*i] i<16 |
// release flag i: bar[64*(17+i)] i<16 | xcd elect x: bar[64*(33+x)] x<8
#define BAR_INTS  (64 * 41)

#define COMPILER_FENCE() asm volatile("" ::: "memory")

__device__ __forceinline__ float sigm(float x) { return 1.f / (1.f + __expf(-x)); }
__device__ __forceinline__ float tanh_f(float x) {
  float xc = fminf(fmaxf(x, -10.f), 10.f);
  float e = __expf(2.f * xc);
  return (e - 1.f) / (e + 1.f);
}

// write-through store (coherent via MALL)
__device__ __forceinline__ void st64c(void* p, u64 v) {
  __hip_atomic_store((u64*)p, v, __ATOMIC_RELAXED, __HIP_MEMORY_SCOPE_AGENT);
}

__global__ void bar_init(int* bar) {
  int i = threadIdx.x;
  #pragma unroll
  for (int k = 0; k < 3; ++k) {
    int idx = i + k * 1024;
    if (idx < BAR_INTS) bar[idx] = 0;
  }
}

// R9 = R8 chassis (flattened push-cascade barrier, 4-wave shadow, late inv,
// wave0 h+out stores) with the GEMM inner structure changed from inline
// dependent-chain loads (VGPR=48 -> ~8 serialized MALL latencies) to a
// WITHIN-PHASE burst: loadB issues all 64 u64 loads (128 VGPRs, one
// latency + BW drain), mfmaQ consumes them immediately. Every loadB/mfmaQ
// pair is contained in one phase -- q is DEAD at every sync point, honoring
// the R3-R6 empirical rule (no operand-register carry across syncs).
// The post-WAIT COMPILER_FENCE pins the ih burst below the grid barrier.
__global__ __launch_bounds__(NTHR, 1) void lstm_kernel(
    const float* __restrict__ x0, const float* __restrict__ h0,
    const float* __restrict__ c0, const float* __restrict__ Wih,
    const float* __restrict__ Whh, const float* __restrict__ bih,
    const float* __restrict__ bhh, const int* __restrict__ lenp,
    float* __restrict__ out, int* __restrict__ bar, f16* __restrict__ planes)
{
  extern __shared__ char smem[];
  f16*   Alds  = (f16*)smem;
  float* scr   = (float*)(smem + SCR_OFF);
  float* cS    = (float*)(smem + C_OFF);
  float* biasS = (float*)(smem + BIAS_OFF);
  f16*   hS    = (f16*)(smem + HS_OFF);     // [n][j] transpose buffer

  const int tid  = threadIdx.x;
  const int blk  = blockIdx.x;
  const int wave = tid >> 6;
  const int lane = tid & 63;
  const int quad = lane >> 4;
  const int l15  = lane & 15;
  const int T    = *lenp;

  f16* l0P[2] = { planes,             planes + PLANE };
  f16* l1P[2] = { planes + 2 * PLANE, planes + 3 * PLANE };
  f16* xP     =   planes + 4 * PLANE;

  const int leafid = blk & 15;
  int* leaf  = bar + 64 * leafid;
  int* relme = bar + 64 * (17 + leafid);

  // ---- physical XCD id + one-time leader election ----
  unsigned xcc;
  asm volatile("s_getreg_b32 %0, hwreg(HW_REG_XCC_ID)" : "=s"(xcc));
  xcc &= 7;
  int is_leader = 0;
  if (tid == 0) {
    int p = __hip_atomic_fetch_add(bar + 64 * (33 + xcc), 1, __ATOMIC_RELAXED,
                                   __HIP_MEMORY_SCOPE_AGENT);
    is_leader = (p == 0);
  }

  // ---- stage weights (f32 -> f16) into LDS ----
  {
    int r    = tid >> 2;
    int part = tid & 3;
    int l    = r >> 5;
    int m    = (r >> 1) & 15;
    int half = r & 1;
    int g    = m >> 2, j = m & 3;
    size_t grow = (size_t)g * HID + blk * 4 + j;
    const float* srcW = (half ? Whh : Wih) + ((size_t)l * 4 * HID + grow) * HID + part * 256;
    f16x8* dst = (f16x8*)(Alds + (size_t)(l * 16 + m) * AROW + half * HID + part * 256);
    const float4* s4 = (const float4*)srcW;
    #pragma unroll 4
    for (int i = 0; i < 32; ++i) {
      float4 w0 = s4[2 * i], w1 = s4[2 * i + 1];
      f16x8 o = {(f16)w0.x, (f16)w0.y, (f16)w0.z, (f16)w0.w,
                 (f16)w1.x, (f16)w1.y, (f16)w1.z, (f16)w1.w};
      dst[i] = o;
    }
  }
  // ---- biases ----
  if (tid < 32) {
    int l = tid >> 4, m = tid & 15;
    int g = m >> 2, j = m & 3;
    size_t row = (size_t)g * HID + blk * 4 + j;
    biasS[l * 16 + m] = bih[(size_t)l * 4 * HID + row] + bhh[(size_t)l * 4 * HID + row];
  }
  // ---- c state (LDS, CU-local) ----
  {
    int j = tid >> 6, n = tid & 63;
    #pragma unroll
    for (int l = 0; l < 2; ++l)
      cS[l * 256 + j * 64 + n] =
          c0[(size_t)l * NBAT * HID + (size_t)n * HID + blk * 4 + j];
  }
  // ---- h0 -> parity-1 planes (block-contiguous, 8B/lane) ----
  if (tid < 128) {
    int l = tid >> 6, n = tid & 63;
    const float* hp = h0 + (size_t)l * NBAT * HID + (size_t)n * HID + blk * 4;
    union { u64 q; f16 h[4]; } pk;
    pk.h[0] = (f16)hp[0]; pk.h[1] = (f16)hp[1]; pk.h[2] = (f16)hp[2]; pk.h[3] = (f16)hp[3];
    st64c((l == 0 ? l0P[1] : l1P[1]) + blk * 256 + n * 4, pk.q);
  }
  // ---- x0 -> xP (each block stages its own 4-unit slot) ----
  if (tid < 64) {
    int n = tid;
    const float* xp = x0 + (size_t)n * HID + blk * 4;
    union { u64 q; f16 h[4]; } pk;
    pk.h[0] = (f16)xp[0]; pk.h[1] = (f16)xp[1]; pk.h[2] = (f16)xp[2]; pk.h[3] = (f16)xp[3];
    st64c(xP + blk * 256 + n * 4, pk.q);
  }
  // one-time safety inv (poison/stale lines) before first arrival
  if (wave == 0) asm volatile("buffer_inv sc1" ::: "memory");

  // ---- split grid barrier (R8, proven): flattened push cascade ----
  int epoch = 1;

  #define ARRIVE()                                                              \
    do {                                                                        \
      asm volatile("s_waitcnt vmcnt(0)" ::: "memory");                          \
      if (tid == 0) {                                                           \
        int prev = __hip_atomic_fetch_add(leaf, 1, __ATOMIC_RELAXED,            \
                                          __HIP_MEMORY_SCOPE_AGENT);            \
        if (prev == 16 * epoch - 1) {                                           \
          _Pragma("unroll")                                                     \
          for (int i_ = 0; i_ < 16; ++i_)                                       \
            (void)__hip_atomic_fetch_add(bar + 64 * (17 + i_), 1,               \
                                         __ATOMIC_RELAXED,                      \
                                         __HIP_MEMORY_SCOPE_AGENT);             \
        }                                                                       \
      }                                                                         \
    } while (0)

  #define WAIT_REL()                                                            \
    do {                                                                        \
      if (tid == 0) {                                                           \
        while (__hip_atomic_fetch_add(relme, 0, __ATOMIC_RELAXED,               \
                                      __HIP_MEMORY_SCOPE_AGENT) < 16 * epoch)   \
          __builtin_amdgcn_s_sleep(1);                                          \
      }                                                                         \
      epoch++;                                                                  \
      __syncthreads();                                                          \
      COMPILER_FENCE();                                                         \
    } while (0)

  // initial barrier: staging used waves 0-1, so every wave drains its own
  // stores, converges, then tid0 arrives
  asm volatile("s_waitcnt vmcnt(0)" ::: "memory");
  __syncthreads();
  ARRIVE();
  WAIT_REL();

  const f16x8* Av = (const f16x8*)Alds;
  const f32x4 fz = {0.f, 0.f, 0.f, 0.f};
  f32x4 a0, a1, a2, a3;
  u64 q[8][8];                 // burst buffer: 128 VGPRs, DEAD at every sync

  // burst-issue this wave's full K=1024 B-slice of a plane (one latency +
  // BW drain instead of 8 serialized dependent batches at VGPR=48)
  auto loadB = [&](const f16* psrc) {
    const f16* p0 = psrc + (wave * 64 + quad * 2) * 256 + l15 * 4;
    #pragma unroll
    for (int kk = 0; kk < 8; ++kk) {
      const f16* k0 = p0 + kk * 2048;
      q[kk][0] = *(const u64*)(k0 +   0);
      q[kk][1] = *(const u64*)(k0 + 256);
      q[kk][2] = *(const u64*)(k0 +  64);
      q[kk][3] = *(const u64*)(k0 + 320);
      q[kk][4] = *(const u64*)(k0 + 128);
      q[kk][5] = *(const u64*)(k0 + 384);
      q[kk][6] = *(const u64*)(k0 + 192);
      q[kk][7] = *(const u64*)(k0 + 448);
    }
  };
  // MFMA chain consuming q, A-row base aoff (same mapping as inline R8)
  auto mfmaQ = [&](int aoff) {
    #pragma unroll
    for (int kk = 0; kk < 8; ++kk) {
      f16x8 af = Av[aoff + kk * 4];
      union { u64 qq[2]; f16x8 v; } b0, b1, b2, b3;
      b0.qq[0] = q[kk][0]; b0.qq[1] = q[kk][1];
      b1.qq[0] = q[kk][2]; b1.qq[1] = q[kk][3];
      b2.qq[0] = q[kk][4]; b2.qq[1] = q[kk][5];
      b3.qq[0] = q[kk][6]; b3.qq[1] = q[kk][7];
      a0 = __builtin_amdgcn_mfma_f32_16x16x32_f16(af, b0.v, a0, 0, 0, 0);
      a1 = __builtin_amdgcn_mfma_f32_16x16x32_f16(af, b1.v, a1, 0, 0, 0);
      a2 = __builtin_amdgcn_mfma_f32_16x16x32_f16(af, b2.v, a2, 0, 0, 0);
      a3 = __builtin_amdgcn_mfma_f32_16x16x32_f16(af, b3.v, a3, 0, 0, 0);
    }
  };

  // ---- prologue: hh(t=0,l=0) from the initial h0 plane (parity 1) ----
  // loadB+mfmaQ contained here; q dead before p=0's ih loadB reuses it.
  a0 = fz; a1 = fz; a2 = fz; a3 = fz;
  loadB(l0P[1]);
  mfmaQ((0 * 16 + l15) * AVEC + 128 + wave * 32 + quad);

  const int NP = 2 * T;
  #pragma unroll 1
  for (int p = 0; p < NP; ++p) {
    const int L = p & 1, t = p >> 1, wp = t & 1, rp = wp ^ 1;
    if (p) WAIT_REL();   // ends in COMPILER_FENCE: ih burst stays below

    // ---- ih-GEMM(p): within-phase burst + consume ----
    const f16* pIh = L ? l0P[wp] : (t ? l1P[rp] : xP);
    loadB(pIh);
    mfmaQ((L * 16 + l15) * AVEC + wave * 32 + quad);   // ih on carried hh

    // ---- partials (hh(p)+ih(p)) to LDS scratch ----
    float* sc = scr + wave * 1024;
    #pragma unroll
    for (int r = 0; r < 4; ++r) {
      int base = (quad * 4 + r) * 64 + l15;
      sc[base +  0] = a0[r];
      sc[base + 16] = a1[r];
      sc[base + 32] = a2[r];
      sc[base + 48] = a3[r];
    }
    __syncthreads();

    // ---- elementwise: thread = (unit j, batch n) ----
    {
      int j = tid >> 6, n = tid & 63;
      float gate[4];
      #pragma unroll
      for (int g = 0; g < 4; ++g) {
        int b0i = (g * 4 + j) * 64 + n;
        gate[g] = scr[b0i] + scr[1024 + b0i] + scr[2048 + b0i] + scr[3072 + b0i]
                + biasS[L * 16 + g * 4 + j];
      }
      float cold = cS[L * 256 + j * 64 + n];
      float cn = sigm(gate[1]) * cold + sigm(gate[0]) * tanh_f(gate[2]);
      float hn = sigm(gate[3]) * tanh_f(cn);
      cS[L * 256 + j * 64 + n] = cn;
      hS[n * 4 + j] = (f16)hn;
    }
    __syncthreads();

    // ---- h store: ONE contiguous 512B chunk per block (+ out on L==1) ----
    if (tid < 64) {
      int n = tid;
      union { u64 q; f16 h[4]; } pk;
      pk.q = *(const u64*)(hS + n * 4);
      st64c((L == 0 ? l0P[wp] : l1P[wp]) + blk * 256 + n * 4, pk.q);
      if (L == 1) {
        union { u64 q; float f[2]; } o0, o1;
        o0.f[0] = (float)pk.h[0]; o0.f[1] = (float)pk.h[1];
        o1.f[0] = (float)pk.h[2]; o1.f[1] = (float)pk.h[3];
        float* op = out + (size_t)n * T * HID + (size_t)t * HID + blk * 4;
        st64c(op, o0.q);
        st64c(op + 2, o1.q);
      }
    }

    if (p < NP - 1) {
      // ARRIVE: wave0 drains its stores + fires arrival (waves 1-3 pass
      // straight through). Shadow = hh(p+1), SELF-CONTAINED burst+consume
      // (operand visible since WAIT(p-1); parity double-buffering protects
      // the read window). Same plane ih just read -> L2-hot.
      ARRIVE();
      const f16* pSh = L ? l0P[wp] : l1P[rp];
      a0 = fz; a1 = fz; a2 = fz; a3 = fz;
      loadB(pSh);
      mfmaQ(((L ^ 1) * 16 + l15) * AVEC + 128 + wave * 32 + quad);
      // leader inv AFTER shadow reads: clears stale lines for next slot's
      // plane without evicting this slot's hot lines
      if (is_leader) asm volatile("buffer_inv sc1" ::: "memory");
    } else {
      asm volatile("s_waitcnt vmcnt(0)" ::: "memory");
    }
  }
}

extern "C" void kernel_launch(void* const* d_in, const int* in_sizes, int n_in,
                              void* d_out, int out_size, void* d_ws, size_t ws_size,
                              hipStream_t stream) {
  const float* x0  = (const float*)d_in[0];
  const float* h0  = (const float*)d_in[1];
  const float* c0  = (const float*)d_in[2];
  const float* Wih = (const float*)d_in[3];
  const float* Whh = (const float*)d_in[4];
  const float* bih = (const float*)d_in[5];
  const float* bhh = (const float*)d_in[6];
  const int* lenp  = (const int*)d_in[7];
  float* out = (float*)d_out;

  int* bar    = (int*)d_ws;
  f16* planes = (f16*)((char*)d_ws + 16384);   // 5 planes x 128 KB

  hipFuncSetAttribute((const void*)lstm_kernel,
                      hipFuncAttributeMaxDynamicSharedMemorySize, LDS_BYTES);

  bar_init<<<1, 1024, 0, stream>>>(bar);

  void* args[] = {&x0, &h0, &c0, &Wih, &Whh, &bih, &bhh, &lenp, &out, &bar, &planes};
  hipLaunchCooperativeKernel((void*)lstm_kernel, dim3(NBLK), dim3(NTHR),
                             args, LDS_BYTES, stream);
}